// Round 20
// baseline (136.813 us; speedup 1.0000x reference)
//
#include <hip/hip_runtime.h>
#include <math.h>

#define D 128
#define ST 64       // hz supertile rows
#define GBIN 256    // genes per radix bin
#define CAP 6144    // LDS-staged edges per bin in fill3b
#define BCAP 8192   // capacity-padded bin size (mean 5115, +43 sigma)
#define BK2_E 8     // edges/thread per bucket2 batch (batch 2048)
#define NBMAX 512
#define BK_BLOCKS 1024  // bucket-sweep blocks (977 active at E=2M)

typedef short bf16x8 __attribute__((ext_vector_type(8)));
typedef short bf16x4 __attribute__((ext_vector_type(4)));
typedef float f32x4 __attribute__((ext_vector_type(4)));
typedef float f32x2 __attribute__((ext_vector_type(2)));

#if __has_builtin(__builtin_amdgcn_cvt_pk_f32_fp8) && __has_builtin(__builtin_amdgcn_cvt_pk_fp8_f32)
#define HW_FP8 1
#else
#define HW_FP8 0
#endif

__device__ inline unsigned short f2bf(float f) {
    union { float f; unsigned u; } v; v.f = f;
    unsigned r = v.u + 0x7fff + ((v.u >> 16) & 1);   // RNE
    return (unsigned short)(r >> 16);
}

// ---- fp8 e4m3fn software encode/decode (fallback when no HW cvt) ----
__device__ inline unsigned f2fp8(float f) {
    union { float f; unsigned u; } v; v.f = f;
    unsigned s = v.u >> 31;
    unsigned mag = v.u & 0x7fffffffu;
    if (mag > 0x43E00000u) mag = 0x43E00000u;       // clamp to 448
    unsigned r = mag + 0x7FFFFu + ((mag >> 20) & 1); // RNE to 3-bit mantissa
    int e = (int)(r >> 23) - 120;
    unsigned out;
    if (e <= 0) {
        float ax;
        { union { unsigned u; float f; } w; w.u = mag; ax = w.f; }
        int m = (int)(ax * 512.0f + 0.5f);
        out = (m > 7) ? 8u : (unsigned)m;            // 8 == e=1,m=0
    } else {
        out = ((unsigned)e << 3) | ((r >> 20) & 7);
    }
    return (s << 7) | out;
}
__device__ inline float fp8dec(unsigned b) {
    unsigned s = b >> 7, em = b & 0x7f;
    union { unsigned u; float f; } w;
    w.u = (em << 20) + 0x3C000000u;
    float v = (em >= 8) ? w.f : (float)(int)em * 0.001953125f;  // denorm: m*2^-9
    return s ? -v : v;
}

// ---- packed fp8 word encode/decode (HW when available) ----
__device__ inline unsigned pack_fp8x4(float4 a) {
#if HW_FP8
    int r = __builtin_amdgcn_cvt_pk_fp8_f32(a.x, a.y, 0, false);
    r = __builtin_amdgcn_cvt_pk_fp8_f32(a.z, a.w, r, true);
    return (unsigned)r;
#else
    return f2fp8(a.x) | (f2fp8(a.y) << 8) | (f2fp8(a.z) << 16) | (f2fp8(a.w) << 24);
#endif
}
__device__ inline void unpack_fp8x4_add(unsigned w, f32x2* acc01, f32x2* acc23) {
#if HW_FP8
    f32x2 p0 = __builtin_amdgcn_cvt_pk_f32_fp8(w, false);
    f32x2 p1 = __builtin_amdgcn_cvt_pk_f32_fp8(w, true);
    *acc01 += p0;
    *acc23 += p1;
#else
    f32x2 p0 = { fp8dec(w & 0xff), fp8dec((w >> 8) & 0xff) };
    f32x2 p1 = { fp8dec((w >> 16) & 0xff), fp8dec((w >> 24) & 0xff) };
    *acc01 += p0;
    *acc23 += p1;
#endif
}

// ---------- fused bucket2 + cvt: blocks [0,BK_BLOCKS) bucket edges; rest convert ----
// bcur is a RELATIVE cursor (memset 0); pos = bin*BCAP + rel.
__global__ __launch_bounds__(256) void bucket2_cvt_kernel(
    const int* __restrict__ esrc, const int* __restrict__ edst,
    int* __restrict__ bcur, unsigned* __restrict__ pairs2, int E, int nbin,
    const float* __restrict__ xd, unsigned char* __restrict__ xdb8, int nxd,
    const float* __restrict__ w0, const float* __restrict__ w1,
    const float* __restrict__ w2, const float* __restrict__ w3,
    unsigned short* __restrict__ t0, unsigned short* __restrict__ t1,
    unsigned short* __restrict__ t2, unsigned short* __restrict__ t3)
{
    int blk = blockIdx.x;
    if (blk >= BK_BLOCKS) {
        int b = blk - BK_BLOCKS;
        if (b < nxd) {
            int i = b * 256 + threadIdx.x;   // one uint2 (8 fp8) per thread
            float4 a = ((const float4*)xd)[i * 2];
            float4 c = ((const float4*)xd)[i * 2 + 1];
            ((uint2*)xdb8)[i] = make_uint2(pack_fp8x4(a), pack_fp8x4(c));
        } else {
            int m = b - nxd;
            const float* src = m == 0 ? w0 : m == 1 ? w1 : m == 2 ? w2 : w3;
            unsigned short* dst = m == 0 ? t0 : m == 1 ? t1 : m == 2 ? t2 : t3;
            for (int idx = threadIdx.x; idx < D * D; idx += 256) {
                int k = idx >> 7, n = idx & 127;
                dst[n * D + k] = f2bf(src[idx]);
            }
        }
        return;
    }

    __shared__ int lcount[NBMAX];
    __shared__ int lbase[NBMAX];
    int t = threadIdx.x;
    const int batch = 256 * BK2_E;   // 2048 edges per block-iteration
    for (long long base = (long long)blk * batch; base < E;
         base += (long long)BK_BLOCKS * batch) {
        for (int b = t; b < nbin; b += 256) lcount[b] = 0;
        __syncthreads();
        int bb[BK2_E], rr[BK2_E];
        unsigned pv[BK2_E];
        #pragma unroll
        for (int j = 0; j < BK2_E; ++j) {
            int e = (int)base + t + j * 256;   // coalesced per sub-batch
            bb[j] = -1;
            if (e < E) {
                int dd = __builtin_nontemporal_load(&edst[e]);
                int ss = __builtin_nontemporal_load(&esrc[e]);
                int bin = dd >> 8;             // GBIN = 256
                bb[j] = bin;
                pv[j] = ((unsigned)(dd & (GBIN - 1)) << 16) | (unsigned)ss;
                rr[j] = atomicAdd(&lcount[bin], 1);
            }
        }
        __syncthreads();
        for (int b = t; b < nbin; b += 256)
            lbase[b] = lcount[b] ? atomicAdd(&bcur[b], lcount[b]) : 0;
        __syncthreads();
        #pragma unroll
        for (int j = 0; j < BK2_E; ++j)
            if (bb[j] >= 0) {
                int rel = lbase[bb[j]] + rr[j];
                if (rel < BCAP)                 // overflow guard (P~0 at 43 sigma)
                    pairs2[(size_t)bb[j] * BCAP + rel] = pv[j];
            }
        __syncthreads();   // lcount reset next iteration
    }
}

// ---------- fill3b (512 thr): per-bin gene-histogram + scan -> offs/oend + LDS scatter ----
__global__ __launch_bounds__(512) void fill3b_kernel(
    const unsigned* __restrict__ pairs2, const int* __restrict__ bcur,
    int* __restrict__ offs, int* __restrict__ oend,
    unsigned short* __restrict__ csr, int ngene)
{
    __shared__ int lhist[GBIN];
    __shared__ int lofs[GBIN];
    __shared__ int lcur[GBIN];
    __shared__ unsigned short stage[CAP];
    int b = blockIdx.x;
    int t = threadIdx.x;
    int g0 = b * GBIN;
    int ng = min(GBIN, ngene - g0);
    int n = min(bcur[b], BCAP);      // relative count
    int sb = b * BCAP;
    int se = sb + n;

    if (t < GBIN) lhist[t] = 0;
    __syncthreads();
    for (int i = sb + t; i < se; i += 512)
        atomicAdd(&lhist[pairs2[i] >> 16], 1);
    __syncthreads();
    int v = (t < GBIN) ? lhist[t] : 0;
    if (t < GBIN) lofs[t] = v;
    __syncthreads();
    for (int off = 1; off < GBIN; off <<= 1) {
        int add = (t >= off && t < GBIN) ? lofs[t - off] : 0;
        __syncthreads();
        if (t < GBIN) lofs[t] += add;
        __syncthreads();
    }
    int myofs = (t < GBIN) ? (lofs[t] - v) : 0;   // exclusive
    if (t < GBIN) {
        lcur[t] = myofs;
        if (t < ng) {
            offs[g0 + t] = sb + myofs;       // dense 1KB runs
            oend[g0 + t] = sb + myofs + v;
        }
    }
    __syncthreads();

    if (n <= CAP) {
        for (int i = sb + t; i < se; i += 512) {
            unsigned u = pairs2[i];
            int pos = atomicAdd(&lcur[u >> 16], 1);
            stage[pos] = (unsigned short)(u & 0xffffu);
        }
        __syncthreads();
        for (int i = t; i < n; i += 512)
            csr[sb + i] = stage[i];
    } else {   // overflow fallback: correctness-preserving global scatter
        for (int i = sb + t; i < se; i += 512) {
            unsigned u = pairs2[i];
            int pos = atomicAdd(&lcur[u >> 16], 1);
            csr[sb + pos] = (unsigned short)(u & 0xffffu);
        }
    }
}

// ---------- gather: mean_bf16[row] = mean over fp8 neighbors (HW cvt, 4 ILP chains) ----
__global__ __launch_bounds__(256, 6) void gather_kernel(
    const int* __restrict__ offs, const int* __restrict__ oend,
    const unsigned short* __restrict__ csr,
    const unsigned char* __restrict__ xdb8, unsigned short* __restrict__ meanb,
    int ngene)
{
    int tid = threadIdx.x;
    int r = tid >> 4, c = tid & 15;
    int row = blockIdx.x * 16 + r;
    if (row >= ngene) return;
    int beg = offs[row], end = oend[row];
    const uint2* tab = (const uint2*)xdb8;   // 16 uint2 per row
    f32x2 a0[4] = {{0,0},{0,0},{0,0},{0,0}};
    f32x2 a1[4] = {{0,0},{0,0},{0,0},{0,0}};
    f32x2 a2[4] = {{0,0},{0,0},{0,0},{0,0}};
    f32x2 a3[4] = {{0,0},{0,0},{0,0},{0,0}};
    int i = beg;
    for (; i + 4 <= end; i += 4) {
        int s0 = csr[i], s1 = csr[i + 1], s2 = csr[i + 2], s3 = csr[i + 3];
        uint2 v0 = tab[s0 * 16 + c];
        uint2 v1 = tab[s1 * 16 + c];
        uint2 v2 = tab[s2 * 16 + c];
        uint2 v3 = tab[s3 * 16 + c];
        unpack_fp8x4_add(v0.x, &a0[0], &a0[1]);
        unpack_fp8x4_add(v0.y, &a0[2], &a0[3]);
        unpack_fp8x4_add(v1.x, &a1[0], &a1[1]);
        unpack_fp8x4_add(v1.y, &a1[2], &a1[3]);
        unpack_fp8x4_add(v2.x, &a2[0], &a2[1]);
        unpack_fp8x4_add(v2.y, &a2[2], &a2[3]);
        unpack_fp8x4_add(v3.x, &a3[0], &a3[1]);
        unpack_fp8x4_add(v3.y, &a3[2], &a3[3]);
    }
    for (; i < end; ++i) {
        int s0 = csr[i];
        uint2 v0 = tab[s0 * 16 + c];
        unpack_fp8x4_add(v0.x, &a0[0], &a0[1]);
        unpack_fp8x4_add(v0.y, &a0[2], &a0[3]);
    }
    float inv = 1.0f / fmaxf((float)(end - beg), 1.0f);
    bf16x8 o;
    #pragma unroll
    for (int j = 0; j < 4; ++j) {
        f32x2 s = (a0[j] + a1[j]) + (a2[j] + a3[j]);
        o[j * 2]     = (short)f2bf(s[0] * inv);
        o[j * 2 + 1] = (short)f2bf(s[1] * inv);
    }
    ((bf16x8*)meanb)[row * 16 + c] = o;
}

// ---------- fused h+z MFMA: 64-row supertile, pipelined stage, 2 barriers/tile ----------
__global__ __launch_bounds__(512, 2) void hz_kernel(
    const unsigned short* __restrict__ meanb, const float* __restrict__ xg,
    const float* __restrict__ eps,
    const unsigned short* __restrict__ WlT, const unsigned short* __restrict__ WrT,
    const unsigned short* __restrict__ muT, const unsigned short* __restrict__ lvT,
    const float* __restrict__ bl, const float* __restrict__ mub,
    const float* __restrict__ lvb, float* __restrict__ z, int ngene, int nst)
{
    __shared__ unsigned short mean_s[ST][132];  // +4 pad
    __shared__ unsigned short xg_s[ST][132];
    __shared__ unsigned short h_s[ST][132];

    int tid = threadIdx.x;
    int wave = tid >> 6;
    int lane = tid & 63;
    int lr = lane & 15;
    int lg = lane >> 4;
    int cb = wave * 16;
    int nb = cb + lg * 4;          // this lane's 4 consecutive output cols

    int row0 = tid >> 4, c0 = tid & 15;   // stage slot 0 (rows 0..31)
    int row1 = row0 + 32;                  // stage slot 1 (rows 32..63)

    float4 bl4 = *(const float4*)&bl[nb];
    float4 mb4 = *(const float4*)&mub[nb];
    float4 lb4 = *(const float4*)&lvb[nb];

    bf16x8 pm0, pm1;
    f32x4 px00, px01, px10, px11;

#define LOAD_TILE(stv) do {                                              \
        int rb_ = (stv) * ST;                                            \
        int g0_ = rb_ + row0; if (g0_ >= ngene) g0_ = ngene - 1;         \
        int g1_ = rb_ + row1; if (g1_ >= ngene) g1_ = ngene - 1;         \
        pm0 = *(const bf16x8*)&meanb[(size_t)g0_ * D + c0 * 8];          \
        pm1 = *(const bf16x8*)&meanb[(size_t)g1_ * D + c0 * 8];          \
        const f32x4* xp0_ = (const f32x4*)&xg[(size_t)g0_ * D + c0 * 8]; \
        const f32x4* xp1_ = (const f32x4*)&xg[(size_t)g1_ * D + c0 * 8]; \
        px00 = xp0_[0]; px01 = xp0_[1];                                  \
        px10 = xp1_[0]; px11 = xp1_[1];                                  \
    } while (0)

    if (blockIdx.x < nst) LOAD_TILE(blockIdx.x);

    for (int st = blockIdx.x; st < nst; st += gridDim.x) {
        int rowbase = st * ST;

        // ---- eps prefetch for this tile (consumed in z phase) ----
        f32x4 epr[4];
        #pragma unroll
        for (int rt = 0; rt < 4; ++rt) {
            int orow = rowbase + rt * 16 + lr;
            if (orow >= ngene) orow = ngene - 1;
            epr[rt] = *(const f32x4*)&eps[(size_t)orow * D + nb];
        }

        // ---- stage: write prefetched regs to LDS (cvt xg here) ----
        {
            *(bf16x8*)&mean_s[row0][c0 * 8] = pm0;
            *(bf16x8*)&mean_s[row1][c0 * 8] = pm1;
            bf16x8 v;
            v[0] = (short)f2bf(px00[0]); v[1] = (short)f2bf(px00[1]);
            v[2] = (short)f2bf(px00[2]); v[3] = (short)f2bf(px00[3]);
            v[4] = (short)f2bf(px01[0]); v[5] = (short)f2bf(px01[1]);
            v[6] = (short)f2bf(px01[2]); v[7] = (short)f2bf(px01[3]);
            *(bf16x8*)&xg_s[row0][c0 * 8] = v;
            v[0] = (short)f2bf(px10[0]); v[1] = (short)f2bf(px10[1]);
            v[2] = (short)f2bf(px10[2]); v[3] = (short)f2bf(px10[3]);
            v[4] = (short)f2bf(px11[0]); v[5] = (short)f2bf(px11[1]);
            v[6] = (short)f2bf(px11[2]); v[7] = (short)f2bf(px11[3]);
            *(bf16x8*)&xg_s[row1][c0 * 8] = v;
        }

        // ---- issue next tile's global loads BEFORE the barrier ----
        int stn = st + gridDim.x;
        if (stn < nst) LOAD_TILE(stn);

        __syncthreads();   // barrier1: stage visible; also fences z(prev) vs h(this)

        // ---- h phase ----
        {
            bf16x8 wl[4], wr[4];
            #pragma unroll
            for (int kc = 0; kc < 4; ++kc) {
                int koff = kc * 32 + lg * 8;
                wl[kc] = *(const bf16x8*)&WlT[(cb + lr) * D + koff];
                wr[kc] = *(const bf16x8*)&WrT[(cb + lr) * D + koff];
            }
            #pragma unroll
            for (int rt = 0; rt < 4; ++rt) {
                int r0 = rt * 16 + lr;
                f32x4 accm = {bl4.x, bl4.y, bl4.z, bl4.w};
                f32x4 accx = {0.f, 0.f, 0.f, 0.f};
                #pragma unroll
                for (int kc = 0; kc < 4; ++kc) {
                    int koff = kc * 32 + lg * 8;
                    bf16x8 am = *(const bf16x8*)&mean_s[r0][koff];
                    bf16x8 ax = *(const bf16x8*)&xg_s[r0][koff];
                    accm = __builtin_amdgcn_mfma_f32_16x16x32_bf16(wl[kc], am, accm, 0, 0, 0);
                    accx = __builtin_amdgcn_mfma_f32_16x16x32_bf16(wr[kc], ax, accx, 0, 0, 0);
                }
                bf16x4 hp;
                #pragma unroll
                for (int r = 0; r < 4; ++r) hp[r] = (short)f2bf(accm[r] + accx[r]);
                *(bf16x4*)&h_s[r0][nb] = hp;
            }
        }
        __syncthreads();   // barrier2: h_s complete before z reads

        // ---- z phase (no trailing barrier; next stage touches only mean_s/xg_s) ----
        {
            bf16x8 mu[4], lv[4];
            #pragma unroll
            for (int kc = 0; kc < 4; ++kc) {
                int koff = kc * 32 + lg * 8;
                mu[kc] = *(const bf16x8*)&muT[(cb + lr) * D + koff];
                lv[kc] = *(const bf16x8*)&lvT[(cb + lr) * D + koff];
            }
            #pragma unroll
            for (int rt = 0; rt < 4; ++rt) {
                int r0 = rt * 16 + lr;
                f32x4 zm = {mb4.x, mb4.y, mb4.z, mb4.w};
                f32x4 zl = {lb4.x, lb4.y, lb4.z, lb4.w};
                #pragma unroll
                for (int kc = 0; kc < 4; ++kc) {
                    int koff = kc * 32 + lg * 8;
                    bf16x8 ah = *(const bf16x8*)&h_s[r0][koff];
                    zm = __builtin_amdgcn_mfma_f32_16x16x32_bf16(mu[kc], ah, zm, 0, 0, 0);
                    zl = __builtin_amdgcn_mfma_f32_16x16x32_bf16(lv[kc], ah, zl, 0, 0, 0);
                }
                int orow = rowbase + r0;
                if (orow < ngene) {
                    f32x4 zo;
                    zo[0] = zm[0] + epr[rt][0] * __expf(zl[0]);
                    zo[1] = zm[1] + epr[rt][1] * __expf(zl[1]);
                    zo[2] = zm[2] + epr[rt][2] * __expf(zl[2]);
                    zo[3] = zm[3] + epr[rt][3] * __expf(zl[3]);
                    __builtin_nontemporal_store(zo, (f32x4*)&z[(size_t)orow * D + nb]);
                }
            }
        }
    }
#undef LOAD_TILE
}

extern "C" void kernel_launch(void* const* d_in, const int* in_sizes, int n_in,
                              void* d_out, int out_size, void* d_ws, size_t ws_size,
                              hipStream_t stream)
{
    const float* xd  = (const float*)d_in[0];
    const float* xg  = (const float*)d_in[1];
    const int* esrc  = (const int*)d_in[2];
    const int* edst  = (const int*)d_in[3];
    const float* eps = (const float*)d_in[4];
    const float* Wl  = (const float*)d_in[5];
    const float* bl  = (const float*)d_in[6];
    const float* Wr  = (const float*)d_in[7];
    const float* muW = (const float*)d_in[8];
    const float* mub = (const float*)d_in[9];
    const float* lvW = (const float*)d_in[10];
    const float* lvb = (const float*)d_in[11];

    int E = in_sizes[2];
    int ndis = in_sizes[0] / D;      // 20000
    int ngene = in_sizes[1] / D;     // 100000
    int nbin = (ngene + GBIN - 1) / GBIN;   // 391 (<= NBMAX)

    // ---- ws layout ----
    char* p = (char*)d_ws;
    int* offs = (int*)p;  p += (size_t)ngene * 4;
    int* oend = (int*)p;  p += (size_t)ngene * 4;
    int* bcur = (int*)p;  p += NBMAX * 4;
    p = (char*)(((size_t)p + 255) & ~(size_t)255);
    unsigned char* xdb8 = (unsigned char*)p;  p += (size_t)ndis * D;
    unsigned short* WlT = (unsigned short*)p; p += D * D * 2;
    unsigned short* WrT = (unsigned short*)p; p += D * D * 2;
    unsigned short* muT = (unsigned short*)p; p += D * D * 2;
    unsigned short* lvT = (unsigned short*)p; p += D * D * 2;
    p = (char*)(((size_t)p + 255) & ~(size_t)255);
    unsigned* pairs2 = (unsigned*)p;          p += (size_t)nbin * BCAP * 4;
    unsigned short* csr_src = (unsigned short*)p; p += (size_t)nbin * BCAP * 2;
    p = (char*)(((size_t)p + 255) & ~(size_t)255);
    unsigned short* meanb = (unsigned short*)p;   // ngene*D bf16

    hipMemsetAsync(bcur, 0, NBMAX * sizeof(int), stream);

    int nxd = ndis * D / 8 / 256;    // 1250 blocks for fp8 conversion
    bucket2_cvt_kernel<<<BK_BLOCKS + nxd + 4, 256, 0, stream>>>(
        esrc, edst, bcur, pairs2, E, nbin,
        xd, xdb8, nxd, Wl, Wr, muW, lvW, WlT, WrT, muT, lvT);

    fill3b_kernel<<<nbin, 512, 0, stream>>>(pairs2, bcur, offs, oend, csr_src, ngene);

    gather_kernel<<<(ngene + 15) / 16, 256, 0, stream>>>(offs, oend, csr_src,
                                                         xdb8, meanb, ngene);

    int nst = (ngene + ST - 1) / ST;   // 1563
    hz_kernel<<<512, 512, 0, stream>>>(meanb, xg, eps, WlT, WrT, muT, lvT,
                                       bl, mub, lvb, (float*)d_out, ngene, nst);
}

// Round 21
// 126.860 us; speedup vs baseline: 1.0784x; 1.0784x over previous
//
#include <hip/hip_runtime.h>
#include <math.h>

#define D 128
#define ST 64       // hz supertile rows
#define GBIN 256    // genes per radix bin
#define CAP 6144    // LDS-staged edges per bin in fill3b
#define BCAP 8192   // capacity-padded bin size (mean 5115, +43 sigma)
#define BK2_E 8     // edges/thread (512 thr -> batch 4096, same as R17/R18)
#define NBMAX 512
#define BK_BLOCKS 512   // bucket-sweep blocks in the fused bucket2+cvt grid

typedef short bf16x8 __attribute__((ext_vector_type(8)));
typedef short bf16x4 __attribute__((ext_vector_type(4)));
typedef float f32x4 __attribute__((ext_vector_type(4)));
typedef float f32x2 __attribute__((ext_vector_type(2)));

#if __has_builtin(__builtin_amdgcn_cvt_pk_f32_fp8) && __has_builtin(__builtin_amdgcn_cvt_pk_fp8_f32)
#define HW_FP8 1
#else
#define HW_FP8 0
#endif

__device__ inline unsigned short f2bf(float f) {
    union { float f; unsigned u; } v; v.f = f;
    unsigned r = v.u + 0x7fff + ((v.u >> 16) & 1);   // RNE
    return (unsigned short)(r >> 16);
}

// ---- fp8 e4m3fn software encode/decode (fallback when no HW cvt) ----
__device__ inline unsigned f2fp8(float f) {
    union { float f; unsigned u; } v; v.f = f;
    unsigned s = v.u >> 31;
    unsigned mag = v.u & 0x7fffffffu;
    if (mag > 0x43E00000u) mag = 0x43E00000u;       // clamp to 448
    unsigned r = mag + 0x7FFFFu + ((mag >> 20) & 1); // RNE to 3-bit mantissa
    int e = (int)(r >> 23) - 120;
    unsigned out;
    if (e <= 0) {
        float ax;
        { union { unsigned u; float f; } w; w.u = mag; ax = w.f; }
        int m = (int)(ax * 512.0f + 0.5f);
        out = (m > 7) ? 8u : (unsigned)m;            // 8 == e=1,m=0
    } else {
        out = ((unsigned)e << 3) | ((r >> 20) & 7);
    }
    return (s << 7) | out;
}
__device__ inline float fp8dec(unsigned b) {
    unsigned s = b >> 7, em = b & 0x7f;
    union { unsigned u; float f; } w;
    w.u = (em << 20) + 0x3C000000u;
    float v = (em >= 8) ? w.f : (float)(int)em * 0.001953125f;  // denorm: m*2^-9
    return s ? -v : v;
}

// ---- packed fp8 word encode/decode (HW when available) ----
__device__ inline unsigned pack_fp8x4(float4 a) {
#if HW_FP8
    int r = __builtin_amdgcn_cvt_pk_fp8_f32(a.x, a.y, 0, false);
    r = __builtin_amdgcn_cvt_pk_fp8_f32(a.z, a.w, r, true);
    return (unsigned)r;
#else
    return f2fp8(a.x) | (f2fp8(a.y) << 8) | (f2fp8(a.z) << 16) | (f2fp8(a.w) << 24);
#endif
}
__device__ inline void unpack_fp8x4_add(unsigned w, f32x2* acc01, f32x2* acc23) {
#if HW_FP8
    f32x2 p0 = __builtin_amdgcn_cvt_pk_f32_fp8(w, false);
    f32x2 p1 = __builtin_amdgcn_cvt_pk_f32_fp8(w, true);
    *acc01 += p0;
    *acc23 += p1;
#else
    f32x2 p0 = { fp8dec(w & 0xff), fp8dec((w >> 8) & 0xff) };
    f32x2 p1 = { fp8dec((w >> 16) & 0xff), fp8dec((w >> 24) & 0xff) };
    *acc01 += p0;
    *acc23 += p1;
#endif
}

// ---------- fused bucket2 + cvt (512 thr): blocks [0,512) bucket; rest convert ----
// bcur is a RELATIVE cursor (memset 0); pos = bin*BCAP + rel.
// 512 threads x BK2_E=8 keeps batch=4096 (R17 overhead) with 2x waves of TLP.
__global__ __launch_bounds__(512) void bucket2_cvt_kernel(
    const int* __restrict__ esrc, const int* __restrict__ edst,
    int* __restrict__ bcur, unsigned* __restrict__ pairs2, int E, int nbin,
    const float* __restrict__ xd, unsigned char* __restrict__ xdb8, int nxd,
    const float* __restrict__ w0, const float* __restrict__ w1,
    const float* __restrict__ w2, const float* __restrict__ w3,
    unsigned short* __restrict__ t0, unsigned short* __restrict__ t1,
    unsigned short* __restrict__ t2, unsigned short* __restrict__ t3)
{
    int blk = blockIdx.x;
    if (blk >= BK_BLOCKS) {
        int b = blk - BK_BLOCKS;
        if (b < nxd) {
            int i = b * 512 + threadIdx.x;   // one uint2 (8 fp8) per thread
            float4 a = ((const float4*)xd)[i * 2];
            float4 c = ((const float4*)xd)[i * 2 + 1];
            ((uint2*)xdb8)[i] = make_uint2(pack_fp8x4(a), pack_fp8x4(c));
        } else {
            int m = b - nxd;
            const float* src = m == 0 ? w0 : m == 1 ? w1 : m == 2 ? w2 : w3;
            unsigned short* dst = m == 0 ? t0 : m == 1 ? t1 : m == 2 ? t2 : t3;
            for (int idx = threadIdx.x; idx < D * D; idx += 512) {
                int k = idx >> 7, n = idx & 127;
                dst[n * D + k] = f2bf(src[idx]);
            }
        }
        return;
    }

    __shared__ int lcount[NBMAX];
    __shared__ int lbase[NBMAX];
    int t = threadIdx.x;
    const int batch = 512 * BK2_E;   // 4096 edges per block-iteration
    for (long long base = (long long)blk * batch; base < E;
         base += (long long)BK_BLOCKS * batch) {
        for (int b = t; b < nbin; b += 512) lcount[b] = 0;
        __syncthreads();
        int bb[BK2_E], rr[BK2_E];
        unsigned pv[BK2_E];
        #pragma unroll
        for (int j = 0; j < BK2_E; ++j) {
            int e = (int)base + t + j * 512;   // coalesced per sub-batch
            bb[j] = -1;
            if (e < E) {
                int dd = __builtin_nontemporal_load(&edst[e]);
                int ss = __builtin_nontemporal_load(&esrc[e]);
                int bin = dd >> 8;             // GBIN = 256
                bb[j] = bin;
                pv[j] = ((unsigned)(dd & (GBIN - 1)) << 16) | (unsigned)ss;
                rr[j] = atomicAdd(&lcount[bin], 1);
            }
        }
        __syncthreads();
        for (int b = t; b < nbin; b += 512)
            lbase[b] = lcount[b] ? atomicAdd(&bcur[b], lcount[b]) : 0;
        __syncthreads();
        #pragma unroll
        for (int j = 0; j < BK2_E; ++j)
            if (bb[j] >= 0) {
                int rel = lbase[bb[j]] + rr[j];
                if (rel < BCAP)                 // overflow guard (P~0 at 43 sigma)
                    pairs2[(size_t)bb[j] * BCAP + rel] = pv[j];
            }
        __syncthreads();   // lcount reset next iteration
    }
}

// ---------- fill3b (512 thr): per-bin gene-histogram + scan -> offs/oend + LDS scatter ----
__global__ __launch_bounds__(512) void fill3b_kernel(
    const unsigned* __restrict__ pairs2, const int* __restrict__ bcur,
    int* __restrict__ offs, int* __restrict__ oend,
    unsigned short* __restrict__ csr, int ngene)
{
    __shared__ int lhist[GBIN];
    __shared__ int lofs[GBIN];
    __shared__ int lcur[GBIN];
    __shared__ unsigned short stage[CAP];
    int b = blockIdx.x;
    int t = threadIdx.x;
    int g0 = b * GBIN;
    int ng = min(GBIN, ngene - g0);
    int n = min(bcur[b], BCAP);      // relative count
    int sb = b * BCAP;
    int se = sb + n;

    if (t < GBIN) lhist[t] = 0;
    __syncthreads();
    for (int i = sb + t; i < se; i += 512)
        atomicAdd(&lhist[pairs2[i] >> 16], 1);
    __syncthreads();
    int v = (t < GBIN) ? lhist[t] : 0;
    if (t < GBIN) lofs[t] = v;
    __syncthreads();
    for (int off = 1; off < GBIN; off <<= 1) {
        int add = (t >= off && t < GBIN) ? lofs[t - off] : 0;
        __syncthreads();
        if (t < GBIN) lofs[t] += add;
        __syncthreads();
    }
    int myofs = (t < GBIN) ? (lofs[t] - v) : 0;   // exclusive
    if (t < GBIN) {
        lcur[t] = myofs;
        if (t < ng) {
            offs[g0 + t] = sb + myofs;       // dense 1KB runs
            oend[g0 + t] = sb + myofs + v;
        }
    }
    __syncthreads();

    if (n <= CAP) {
        for (int i = sb + t; i < se; i += 512) {
            unsigned u = pairs2[i];
            int pos = atomicAdd(&lcur[u >> 16], 1);
            stage[pos] = (unsigned short)(u & 0xffffu);
        }
        __syncthreads();
        for (int i = t; i < n; i += 512)
            csr[sb + i] = stage[i];
    } else {   // overflow fallback: correctness-preserving global scatter
        for (int i = sb + t; i < se; i += 512) {
            unsigned u = pairs2[i];
            int pos = atomicAdd(&lcur[u >> 16], 1);
            csr[sb + pos] = (unsigned short)(u & 0xffffu);
        }
    }
}

// ---------- gather: mean_bf16[row] = mean over fp8 neighbors (HW cvt, 4 ILP chains) ----
__global__ __launch_bounds__(256, 6) void gather_kernel(
    const int* __restrict__ offs, const int* __restrict__ oend,
    const unsigned short* __restrict__ csr,
    const unsigned char* __restrict__ xdb8, unsigned short* __restrict__ meanb,
    int ngene)
{
    int tid = threadIdx.x;
    int r = tid >> 4, c = tid & 15;
    int row = blockIdx.x * 16 + r;
    if (row >= ngene) return;
    int beg = offs[row], end = oend[row];
    const uint2* tab = (const uint2*)xdb8;   // 16 uint2 per row
    f32x2 a0[4] = {{0,0},{0,0},{0,0},{0,0}};
    f32x2 a1[4] = {{0,0},{0,0},{0,0},{0,0}};
    f32x2 a2[4] = {{0,0},{0,0},{0,0},{0,0}};
    f32x2 a3[4] = {{0,0},{0,0},{0,0},{0,0}};
    int i = beg;
    for (; i + 4 <= end; i += 4) {
        int s0 = csr[i], s1 = csr[i + 1], s2 = csr[i + 2], s3 = csr[i + 3];
        uint2 v0 = tab[s0 * 16 + c];
        uint2 v1 = tab[s1 * 16 + c];
        uint2 v2 = tab[s2 * 16 + c];
        uint2 v3 = tab[s3 * 16 + c];
        unpack_fp8x4_add(v0.x, &a0[0], &a0[1]);
        unpack_fp8x4_add(v0.y, &a0[2], &a0[3]);
        unpack_fp8x4_add(v1.x, &a1[0], &a1[1]);
        unpack_fp8x4_add(v1.y, &a1[2], &a1[3]);
        unpack_fp8x4_add(v2.x, &a2[0], &a2[1]);
        unpack_fp8x4_add(v2.y, &a2[2], &a2[3]);
        unpack_fp8x4_add(v3.x, &a3[0], &a3[1]);
        unpack_fp8x4_add(v3.y, &a3[2], &a3[3]);
    }
    for (; i < end; ++i) {
        int s0 = csr[i];
        uint2 v0 = tab[s0 * 16 + c];
        unpack_fp8x4_add(v0.x, &a0[0], &a0[1]);
        unpack_fp8x4_add(v0.y, &a0[2], &a0[3]);
    }
    float inv = 1.0f / fmaxf((float)(end - beg), 1.0f);
    bf16x8 o;
    #pragma unroll
    for (int j = 0; j < 4; ++j) {
        f32x2 s = (a0[j] + a1[j]) + (a2[j] + a3[j]);
        o[j * 2]     = (short)f2bf(s[0] * inv);
        o[j * 2 + 1] = (short)f2bf(s[1] * inv);
    }
    ((bf16x8*)meanb)[row * 16 + c] = o;
}

// ---------- fused h+z MFMA: 64-row supertile, pipelined stage, 2 barriers/tile ----------
__global__ __launch_bounds__(512, 2) void hz_kernel(
    const unsigned short* __restrict__ meanb, const float* __restrict__ xg,
    const float* __restrict__ eps,
    const unsigned short* __restrict__ WlT, const unsigned short* __restrict__ WrT,
    const unsigned short* __restrict__ muT, const unsigned short* __restrict__ lvT,
    const float* __restrict__ bl, const float* __restrict__ mub,
    const float* __restrict__ lvb, float* __restrict__ z, int ngene, int nst)
{
    __shared__ unsigned short mean_s[ST][132];  // +4 pad
    __shared__ unsigned short xg_s[ST][132];
    __shared__ unsigned short h_s[ST][132];

    int tid = threadIdx.x;
    int wave = tid >> 6;
    int lane = tid & 63;
    int lr = lane & 15;
    int lg = lane >> 4;
    int cb = wave * 16;
    int nb = cb + lg * 4;          // this lane's 4 consecutive output cols

    int row0 = tid >> 4, c0 = tid & 15;   // stage slot 0 (rows 0..31)
    int row1 = row0 + 32;                  // stage slot 1 (rows 32..63)

    float4 bl4 = *(const float4*)&bl[nb];
    float4 mb4 = *(const float4*)&mub[nb];
    float4 lb4 = *(const float4*)&lvb[nb];

    bf16x8 pm0, pm1;
    f32x4 px00, px01, px10, px11;

#define LOAD_TILE(stv) do {                                              \
        int rb_ = (stv) * ST;                                            \
        int g0_ = rb_ + row0; if (g0_ >= ngene) g0_ = ngene - 1;         \
        int g1_ = rb_ + row1; if (g1_ >= ngene) g1_ = ngene - 1;         \
        pm0 = *(const bf16x8*)&meanb[(size_t)g0_ * D + c0 * 8];          \
        pm1 = *(const bf16x8*)&meanb[(size_t)g1_ * D + c0 * 8];          \
        const f32x4* xp0_ = (const f32x4*)&xg[(size_t)g0_ * D + c0 * 8]; \
        const f32x4* xp1_ = (const f32x4*)&xg[(size_t)g1_ * D + c0 * 8]; \
        px00 = xp0_[0]; px01 = xp0_[1];                                  \
        px10 = xp1_[0]; px11 = xp1_[1];                                  \
    } while (0)

    if (blockIdx.x < nst) LOAD_TILE(blockIdx.x);

    for (int st = blockIdx.x; st < nst; st += gridDim.x) {
        int rowbase = st * ST;

        // ---- eps prefetch for this tile (consumed in z phase) ----
        f32x4 epr[4];
        #pragma unroll
        for (int rt = 0; rt < 4; ++rt) {
            int orow = rowbase + rt * 16 + lr;
            if (orow >= ngene) orow = ngene - 1;
            epr[rt] = *(const f32x4*)&eps[(size_t)orow * D + nb];
        }

        // ---- stage: write prefetched regs to LDS (cvt xg here) ----
        {
            *(bf16x8*)&mean_s[row0][c0 * 8] = pm0;
            *(bf16x8*)&mean_s[row1][c0 * 8] = pm1;
            bf16x8 v;
            v[0] = (short)f2bf(px00[0]); v[1] = (short)f2bf(px00[1]);
            v[2] = (short)f2bf(px00[2]); v[3] = (short)f2bf(px00[3]);
            v[4] = (short)f2bf(px01[0]); v[5] = (short)f2bf(px01[1]);
            v[6] = (short)f2bf(px01[2]); v[7] = (short)f2bf(px01[3]);
            *(bf16x8*)&xg_s[row0][c0 * 8] = v;
            v[0] = (short)f2bf(px10[0]); v[1] = (short)f2bf(px10[1]);
            v[2] = (short)f2bf(px10[2]); v[3] = (short)f2bf(px10[3]);
            v[4] = (short)f2bf(px11[0]); v[5] = (short)f2bf(px11[1]);
            v[6] = (short)f2bf(px11[2]); v[7] = (short)f2bf(px11[3]);
            *(bf16x8*)&xg_s[row1][c0 * 8] = v;
        }

        // ---- issue next tile's global loads BEFORE the barrier ----
        int stn = st + gridDim.x;
        if (stn < nst) LOAD_TILE(stn);

        __syncthreads();   // barrier1: stage visible; also fences z(prev) vs h(this)

        // ---- h phase ----
        {
            bf16x8 wl[4], wr[4];
            #pragma unroll
            for (int kc = 0; kc < 4; ++kc) {
                int koff = kc * 32 + lg * 8;
                wl[kc] = *(const bf16x8*)&WlT[(cb + lr) * D + koff];
                wr[kc] = *(const bf16x8*)&WrT[(cb + lr) * D + koff];
            }
            #pragma unroll
            for (int rt = 0; rt < 4; ++rt) {
                int r0 = rt * 16 + lr;
                f32x4 accm = {bl4.x, bl4.y, bl4.z, bl4.w};
                f32x4 accx = {0.f, 0.f, 0.f, 0.f};
                #pragma unroll
                for (int kc = 0; kc < 4; ++kc) {
                    int koff = kc * 32 + lg * 8;
                    bf16x8 am = *(const bf16x8*)&mean_s[r0][koff];
                    bf16x8 ax = *(const bf16x8*)&xg_s[r0][koff];
                    accm = __builtin_amdgcn_mfma_f32_16x16x32_bf16(wl[kc], am, accm, 0, 0, 0);
                    accx = __builtin_amdgcn_mfma_f32_16x16x32_bf16(wr[kc], ax, accx, 0, 0, 0);
                }
                bf16x4 hp;
                #pragma unroll
                for (int r = 0; r < 4; ++r) hp[r] = (short)f2bf(accm[r] + accx[r]);
                *(bf16x4*)&h_s[r0][nb] = hp;
            }
        }
        __syncthreads();   // barrier2: h_s complete before z reads

        // ---- z phase (no trailing barrier; next stage touches only mean_s/xg_s) ----
        {
            bf16x8 mu[4], lv[4];
            #pragma unroll
            for (int kc = 0; kc < 4; ++kc) {
                int koff = kc * 32 + lg * 8;
                mu[kc] = *(const bf16x8*)&muT[(cb + lr) * D + koff];
                lv[kc] = *(const bf16x8*)&lvT[(cb + lr) * D + koff];
            }
            #pragma unroll
            for (int rt = 0; rt < 4; ++rt) {
                int r0 = rt * 16 + lr;
                f32x4 zm = {mb4.x, mb4.y, mb4.z, mb4.w};
                f32x4 zl = {lb4.x, lb4.y, lb4.z, lb4.w};
                #pragma unroll
                for (int kc = 0; kc < 4; ++kc) {
                    int koff = kc * 32 + lg * 8;
                    bf16x8 ah = *(const bf16x8*)&h_s[r0][koff];
                    zm = __builtin_amdgcn_mfma_f32_16x16x32_bf16(mu[kc], ah, zm, 0, 0, 0);
                    zl = __builtin_amdgcn_mfma_f32_16x16x32_bf16(lv[kc], ah, zl, 0, 0, 0);
                }
                int orow = rowbase + r0;
                if (orow < ngene) {
                    f32x4 zo;
                    zo[0] = zm[0] + epr[rt][0] * __expf(zl[0]);
                    zo[1] = zm[1] + epr[rt][1] * __expf(zl[1]);
                    zo[2] = zm[2] + epr[rt][2] * __expf(zl[2]);
                    zo[3] = zm[3] + epr[rt][3] * __expf(zl[3]);
                    __builtin_nontemporal_store(zo, (f32x4*)&z[(size_t)orow * D + nb]);
                }
            }
        }
    }
#undef LOAD_TILE
}

extern "C" void kernel_launch(void* const* d_in, const int* in_sizes, int n_in,
                              void* d_out, int out_size, void* d_ws, size_t ws_size,
                              hipStream_t stream)
{
    const float* xd  = (const float*)d_in[0];
    const float* xg  = (const float*)d_in[1];
    const int* esrc  = (const int*)d_in[2];
    const int* edst  = (const int*)d_in[3];
    const float* eps = (const float*)d_in[4];
    const float* Wl  = (const float*)d_in[5];
    const float* bl  = (const float*)d_in[6];
    const float* Wr  = (const float*)d_in[7];
    const float* muW = (const float*)d_in[8];
    const float* mub = (const float*)d_in[9];
    const float* lvW = (const float*)d_in[10];
    const float* lvb = (const float*)d_in[11];

    int E = in_sizes[2];
    int ndis = in_sizes[0] / D;      // 20000
    int ngene = in_sizes[1] / D;     // 100000
    int nbin = (ngene + GBIN - 1) / GBIN;   // 391 (<= NBMAX)

    // ---- ws layout ----
    char* p = (char*)d_ws;
    int* offs = (int*)p;  p += (size_t)ngene * 4;
    int* oend = (int*)p;  p += (size_t)ngene * 4;
    int* bcur = (int*)p;  p += NBMAX * 4;
    p = (char*)(((size_t)p + 255) & ~(size_t)255);
    unsigned char* xdb8 = (unsigned char*)p;  p += (size_t)ndis * D;
    unsigned short* WlT = (unsigned short*)p; p += D * D * 2;
    unsigned short* WrT = (unsigned short*)p; p += D * D * 2;
    unsigned short* muT = (unsigned short*)p; p += D * D * 2;
    unsigned short* lvT = (unsigned short*)p; p += D * D * 2;
    p = (char*)(((size_t)p + 255) & ~(size_t)255);
    unsigned* pairs2 = (unsigned*)p;          p += (size_t)nbin * BCAP * 4;
    unsigned short* csr_src = (unsigned short*)p; p += (size_t)nbin * BCAP * 2;
    p = (char*)(((size_t)p + 255) & ~(size_t)255);
    unsigned short* meanb = (unsigned short*)p;   // ngene*D bf16

    hipMemsetAsync(bcur, 0, NBMAX * sizeof(int), stream);

    int nxd = ndis * D / 8 / 512;    // 625 blocks for fp8 conversion (512 thr)
    bucket2_cvt_kernel<<<BK_BLOCKS + nxd + 4, 512, 0, stream>>>(
        esrc, edst, bcur, pairs2, E, nbin,
        xd, xdb8, nxd, Wl, Wr, muW, lvW, WlT, WrT, muT, lvT);

    fill3b_kernel<<<nbin, 512, 0, stream>>>(pairs2, bcur, offs, oend, csr_src, ngene);

    gather_kernel<<<(ngene + 15) / 16, 256, 0, stream>>>(offs, oend, csr_src,
                                                         xdb8, meanb, ngene);

    int nst = (ngene + ST - 1) / ST;   // 1563
    hz_kernel<<<512, 512, 0, stream>>>(meanb, xg, eps, WlT, WrT, muT, lvT,
                                       bl, mub, lvb, (float*)d_out, ngene, nst);
}